// Round 1
// baseline (749.381 us; speedup 1.0000x reference)
//
#include <hip/hip_runtime.h>

#define F 128

// ---------------- setup kernels ----------------

__global__ __launch_bounds__(256) void k_init(float* deg, float* cnt, float* gacc, int N, int G) {
    int i = blockIdx.x * 256 + threadIdx.x;
    if (i < N) deg[i] = 1.0f;               // self-loop
    if (i < G) { cnt[i] = 0.0f; gacc[i] = 0.0f; }
}

__global__ __launch_bounds__(256) void k_count(const int* __restrict__ dst, const int* __restrict__ batch,
                                               float* deg, float* cnt, int E, int N) {
    int i = blockIdx.x * 256 + threadIdx.x;
    if (i < E) unsafeAtomicAdd(&deg[dst[i]], 1.0f);
    if (i < N) unsafeAtomicAdd(&cnt[batch[i]], 1.0f);
}

__global__ __launch_bounds__(256) void k_dis(const float* __restrict__ deg, float* __restrict__ dis, int N) {
    int i = blockIdx.x * 256 + threadIdx.x;
    if (i < N) dis[i] = rsqrtf(deg[i]);     // deg >= 1 always (self-loop)
}

// exclusive scan of (deg[i]-1) = real in-degree, 1024 elems/block
__global__ __launch_bounds__(256) void k_scan1(const float* __restrict__ deg, int* __restrict__ pref,
                                               int* __restrict__ bsum, int N) {
    int t = threadIdx.x;
    int base = blockIdx.x * 1024 + t * 4;
    int v[4]; int s = 0;
#pragma unroll
    for (int j = 0; j < 4; ++j) { int idx = base + j; v[j] = (idx < N) ? ((int)deg[idx] - 1) : 0; s += v[j]; }
    int lane = t & 63, w = t >> 6;
    int inc = s;
#pragma unroll
    for (int d = 1; d < 64; d <<= 1) { int o = __shfl_up(inc, d); if (lane >= d) inc += o; }
    __shared__ int wtot[4];
    if (lane == 63) wtot[w] = inc;
    __syncthreads();
    int woff = 0;
#pragma unroll
    for (int i = 0; i < 4; ++i) if (i < w) woff += wtot[i];
    int run = woff + inc - s;               // exclusive prefix of this thread's chunk
#pragma unroll
    for (int j = 0; j < 4; ++j) { int idx = base + j; if (idx < N) pref[idx] = run; run += v[j]; }
    if (t == 255) bsum[blockIdx.x] = woff + inc;
}

__global__ void k_scan2(int* bsum, int B) {
    if (threadIdx.x == 0) { int run = 0; for (int i = 0; i < B; ++i) { int x = bsum[i]; bsum[i] = run; run += x; } }
}

__global__ __launch_bounds__(256) void k_scan3(int* __restrict__ pref, const int* __restrict__ bsum,
                                               int* __restrict__ cursor, int N, int E) {
    int i = blockIdx.x * 256 + threadIdx.x;
    if (i < N) {
        int v = pref[i] + bsum[i >> 10];
        pref[i] = v;
        cursor[i] = v;
    }
    if (i == 0) pref[N] = E;
}

__global__ __launch_bounds__(256) void k_fill(const int* __restrict__ src, const int* __restrict__ dst,
                                              const float* __restrict__ dis, int* __restrict__ cursor,
                                              int* __restrict__ srcs, float* __restrict__ enorm, int E) {
    int e = blockIdx.x * 256 + threadIdx.x;
    if (e < E) {
        int s = src[e], d = dst[e];
        int slot = atomicAdd(&cursor[d], 1);
        srcs[slot] = s;
        enorm[slot] = dis[s] * dis[d];
    }
}

// ---------------- GEMM: Y[N x 128] = X[N x 128] @ W[128 x 128] ----------------
// block: 256 thr, 128 rows; thread: 8 rows x 8 cols (cols 4cg..4cg+3 and 64+4cg..+3 -> 2-way LDS banks = free)
__global__ __launch_bounds__(256) void k_gemm(const float* __restrict__ X, const float* __restrict__ W,
                                              float* __restrict__ Y, int N) {
    __shared__ float Wl[F * F];
    for (int i = threadIdx.x * 4; i < F * F; i += 256 * 4)
        *(float4*)&Wl[i] = *(const float4*)&W[i];
    __syncthreads();
    int cg = threadIdx.x & 15;
    int rg = threadIdx.x >> 4;
    int r0 = blockIdx.x * 128 + rg * 8;
    int ca = cg * 4, cb = 64 + cg * 4;
    float acc[8][8] = {};
    for (int k = 0; k < F; k += 4) {
        float4 xv[8];
#pragma unroll
        for (int j = 0; j < 8; ++j) {
            int r = r0 + j; if (r >= N) r = N - 1;   // clamp: safe duplicate read
            xv[j] = *(const float4*)&X[r * F + k];
        }
#pragma unroll
        for (int kk = 0; kk < 4; ++kk) {
            float4 wa = *(const float4*)&Wl[(k + kk) * F + ca];
            float4 wb = *(const float4*)&Wl[(k + kk) * F + cb];
#pragma unroll
            for (int j = 0; j < 8; ++j) {
                float xs = (&xv[j].x)[kk];
                acc[j][0] += xs * wa.x; acc[j][1] += xs * wa.y; acc[j][2] += xs * wa.z; acc[j][3] += xs * wa.w;
                acc[j][4] += xs * wb.x; acc[j][5] += xs * wb.y; acc[j][6] += xs * wb.z; acc[j][7] += xs * wb.w;
            }
        }
    }
#pragma unroll
    for (int j = 0; j < 8; ++j) {
        int r = r0 + j;
        if (r < N) {
            *(float4*)&Y[r * F + ca] = make_float4(acc[j][0], acc[j][1], acc[j][2], acc[j][3]);
            *(float4*)&Y[r * F + cb] = make_float4(acc[j][4], acc[j][5], acc[j][6], acc[j][7]);
        }
    }
}

// ---------------- aggregation: one wave per node, gather-based (no float atomics) ----------------
__global__ __launch_bounds__(256) void k_agg(const float* __restrict__ hW, const float* __restrict__ dis,
                                             const int* __restrict__ rowptr, const int* __restrict__ srcs,
                                             const float* __restrict__ enorm, const float* __restrict__ bias,
                                             float* __restrict__ out, int N, int relu) {
    int node = blockIdx.x * 4 + (threadIdx.x >> 6);
    if (node >= N) return;
    int lane = threadIdx.x & 63;
    float di = dis[node];
    float sl = di * di;                       // self-loop norm
    float2 acc = *(const float2*)&hW[node * F + lane * 2];
    float2 b = *(const float2*)&bias[lane * 2];
    acc.x = acc.x * sl + b.x;
    acc.y = acc.y * sl + b.y;
    int e0 = rowptr[node], e1 = rowptr[node + 1];
    for (int e = e0; e < e1; ++e) {
        int s = srcs[e]; float nm = enorm[e];
        float2 v = *(const float2*)&hW[s * F + lane * 2];
        acc.x += nm * v.x;
        acc.y += nm * v.y;
    }
    if (relu) { acc.x = fmaxf(acc.x, 0.0f); acc.y = fmaxf(acc.y, 0.0f); }
    *(float2*)&out[node * F + lane * 2] = acc;
}

// layer-2 aggregation fused with mean-pool dot: h2 never materialized
__global__ __launch_bounds__(256) void k_agg_pool(const float* __restrict__ hW, const float* __restrict__ dis,
                                                  const int* __restrict__ rowptr, const int* __restrict__ srcs,
                                                  const float* __restrict__ enorm, const float* __restrict__ bias,
                                                  const float* __restrict__ Wlin, const int* __restrict__ batch,
                                                  float* __restrict__ gacc, int N) {
    int node = blockIdx.x * 4 + (threadIdx.x >> 6);
    if (node >= N) return;
    int lane = threadIdx.x & 63;
    float di = dis[node];
    float sl = di * di;
    float2 acc = *(const float2*)&hW[node * F + lane * 2];
    float2 b = *(const float2*)&bias[lane * 2];
    acc.x = acc.x * sl + b.x;
    acc.y = acc.y * sl + b.y;
    int e0 = rowptr[node], e1 = rowptr[node + 1];
    for (int e = e0; e < e1; ++e) {
        int s = srcs[e]; float nm = enorm[e];
        float2 v = *(const float2*)&hW[s * F + lane * 2];
        acc.x += nm * v.x;
        acc.y += nm * v.y;
    }
    float2 wl = *(const float2*)&Wlin[lane * 2];
    float p = acc.x * wl.x + acc.y * wl.y;
#pragma unroll
    for (int d = 1; d < 64; d <<= 1) p += __shfl_xor(p, d);
    if (lane == 0) unsafeAtomicAdd(&gacc[batch[node]], p);
}

__global__ __launch_bounds__(256) void k_final(const float* __restrict__ gacc, const float* __restrict__ cnt,
                                               const float* __restrict__ blin, float* __restrict__ out, int G) {
    int g = blockIdx.x * 256 + threadIdx.x;
    if (g < G) out[g] = gacc[g] / fmaxf(cnt[g], 1.0f) + blin[0];
}

// ---------------- launch ----------------

extern "C" void kernel_launch(void* const* d_in, const int* in_sizes, int n_in,
                              void* d_out, int out_size, void* d_ws, size_t ws_size,
                              hipStream_t stream) {
    const float* x    = (const float*)d_in[0];
    const int*   ei   = (const int*)d_in[1];
    const int*   batch= (const int*)d_in[2];
    const float* W1   = (const float*)d_in[3];
    const float* b1   = (const float*)d_in[4];
    const float* W2   = (const float*)d_in[5];
    const float* b2   = (const float*)d_in[6];
    const float* Wlin = (const float*)d_in[7];
    const float* blin = (const float*)d_in[8];
    float* out = (float*)d_out;

    const int N = in_sizes[2];          // 100000
    const int E = in_sizes[1] / 2;      // 600000
    const int G = out_size;             // 512
    const int* src = ei;
    const int* dst = ei + E;

    // workspace carve-up (256B aligned)
    char* p = (char*)d_ws;
    auto take = [&](size_t bytes) { char* q = p; p += (bytes + 255) & ~(size_t)255; return q; };
    float* bufA   = (float*)take((size_t)N * F * 4);   // hW
    float* bufB   = (float*)take((size_t)N * F * 4);   // h1
    float* deg    = (float*)take((size_t)N * 4);
    float* dis    = (float*)take((size_t)N * 4);
    int*   rowptr = (int*)  take((size_t)(N + 1) * 4);
    int*   cursor = (int*)  take((size_t)N * 4);
    int*   srcs   = (int*)  take((size_t)E * 4);
    float* enorm  = (float*)take((size_t)E * 4);
    int*   bsum   = (int*)  take(4096);
    float* cnt    = (float*)take((size_t)G * 4);
    float* gacc   = (float*)take((size_t)G * 4);

    const int nbN = (N + 255) / 256;
    const int nbE = (E + 255) / 256;
    const int nbS = (N + 1023) / 1024;

    k_init <<<nbN, 256, 0, stream>>>(deg, cnt, gacc, N, G);
    k_count<<<(E > N ? nbE : nbN), 256, 0, stream>>>(dst, batch, deg, cnt, E, N);
    k_dis  <<<nbN, 256, 0, stream>>>(deg, dis, N);
    k_scan1<<<nbS, 256, 0, stream>>>(deg, rowptr, bsum, N);
    k_scan2<<<1, 64, 0, stream>>>(bsum, nbS);
    k_scan3<<<nbN, 256, 0, stream>>>(rowptr, bsum, cursor, N, E);
    k_fill <<<nbE, 256, 0, stream>>>(src, dst, dis, cursor, srcs, enorm, E);

    const int nbG = (N + 127) / 128;
    const int nbA = (N + 3) / 4;

    // layer 1: hW = x @ W1 ; h1 = relu(agg(hW) + b1)
    k_gemm<<<nbG, 256, 0, stream>>>(x, W1, bufA, N);
    k_agg <<<nbA, 256, 0, stream>>>(bufA, dis, rowptr, srcs, enorm, b1, bufB, N, 1);

    // layer 2 fused with pooling dot
    k_gemm<<<nbG, 256, 0, stream>>>(bufB, W2, bufA, N);
    k_agg_pool<<<nbA, 256, 0, stream>>>(bufA, dis, rowptr, srcs, enorm, b2, Wlin, batch, gacc, N);

    k_final<<<(G + 255) / 256, 256, 0, stream>>>(gacc, cnt, blin, out, G);
}

// Round 2
// 413.927 us; speedup vs baseline: 1.8104x; 1.8104x over previous
//
#include <hip/hip_runtime.h>

#define F 128

// ---------------- setup kernels ----------------

__global__ __launch_bounds__(256) void k_init(float* deg, float* cnt, float* gacc, int N, int G) {
    int i = blockIdx.x * 256 + threadIdx.x;
    if (i < N) deg[i] = 1.0f;               // self-loop
    if (i < G) { cnt[i] = 0.0f; gacc[i] = 0.0f; }
}

__global__ __launch_bounds__(256) void k_count(const int* __restrict__ dst, const int* __restrict__ batch,
                                               float* deg, float* cnt, int E, int N) {
    int i = blockIdx.x * 256 + threadIdx.x;
    if (i < E) unsafeAtomicAdd(&deg[dst[i]], 1.0f);
    if (i < N) unsafeAtomicAdd(&cnt[batch[i]], 1.0f);
}

__global__ __launch_bounds__(256) void k_dis(const float* __restrict__ deg, float* __restrict__ dis, int N) {
    int i = blockIdx.x * 256 + threadIdx.x;
    if (i < N) dis[i] = rsqrtf(deg[i]);     // deg >= 1 always (self-loop)
}

// exclusive scan of (deg[i]-1) = real in-degree, 1024 elems/block
__global__ __launch_bounds__(256) void k_scan1(const float* __restrict__ deg, int* __restrict__ pref,
                                               int* __restrict__ bsum, int N) {
    int t = threadIdx.x;
    int base = blockIdx.x * 1024 + t * 4;
    int v[4]; int s = 0;
#pragma unroll
    for (int j = 0; j < 4; ++j) { int idx = base + j; v[j] = (idx < N) ? ((int)deg[idx] - 1) : 0; s += v[j]; }
    int lane = t & 63, w = t >> 6;
    int inc = s;
#pragma unroll
    for (int d = 1; d < 64; d <<= 1) { int o = __shfl_up(inc, d); if (lane >= d) inc += o; }
    __shared__ int wtot[4];
    if (lane == 63) wtot[w] = inc;
    __syncthreads();
    int woff = 0;
#pragma unroll
    for (int i = 0; i < 4; ++i) if (i < w) woff += wtot[i];
    int run = woff + inc - s;               // exclusive prefix of this thread's chunk
#pragma unroll
    for (int j = 0; j < 4; ++j) { int idx = base + j; if (idx < N) pref[idx] = run; run += v[j]; }
    if (t == 255) bsum[blockIdx.x] = woff + inc;
}

__global__ void k_scan2(int* bsum, int B) {
    if (threadIdx.x == 0) { int run = 0; for (int i = 0; i < B; ++i) { int x = bsum[i]; bsum[i] = run; run += x; } }
}

__global__ __launch_bounds__(256) void k_scan3(int* __restrict__ pref, const int* __restrict__ bsum,
                                               int* __restrict__ cursor, int N, int E) {
    int i = blockIdx.x * 256 + threadIdx.x;
    if (i < N) {
        int v = pref[i] + bsum[i >> 10];
        pref[i] = v;
        cursor[i] = v;
    }
    if (i == 0) pref[N] = E;
}

__global__ __launch_bounds__(256) void k_fill(const int* __restrict__ src, const int* __restrict__ dst,
                                              const float* __restrict__ dis, int* __restrict__ cursor,
                                              int* __restrict__ srcs, float* __restrict__ enorm, int E) {
    int e = blockIdx.x * 256 + threadIdx.x;
    if (e < E) {
        int s = src[e], d = dst[e];
        int slot = atomicAdd(&cursor[d], 1);
        srcs[slot] = s;
        enorm[slot] = dis[s] * dis[d];
    }
}

// w2l = W2 @ Wlin  (128x1); cconst = b2 . Wlin + blin
__global__ __launch_bounds__(128) void k_w2l(const float* __restrict__ W2, const float* __restrict__ Wlin,
                                             const float* __restrict__ b2, const float* __restrict__ blin,
                                             float* __restrict__ w2l, float* __restrict__ cconst) {
    int k = threadIdx.x;
    float s = 0.0f;
    for (int j = 0; j < F; j += 4) {
        float4 w = *(const float4*)&W2[k * F + j];
        float4 l = *(const float4*)&Wlin[j];
        s += w.x * l.x + w.y * l.y + w.z * l.z + w.w * l.w;
    }
    w2l[k] = s;
    __shared__ float sh[F];
    sh[k] = b2[k] * Wlin[k];
    __syncthreads();
    if (k == 0) {
        float c = blin[0];
        for (int j = 0; j < F; ++j) c += sh[j];
        *cconst = c;
    }
}

// ---------------- GEMM: Y[N x 128] = X[N x 128] @ W[128 x 128] ----------------
__global__ __launch_bounds__(256) void k_gemm(const float* __restrict__ X, const float* __restrict__ W,
                                              float* __restrict__ Y, int N) {
    __shared__ float Wl[F * F];
    for (int i = threadIdx.x * 4; i < F * F; i += 256 * 4)
        *(float4*)&Wl[i] = *(const float4*)&W[i];
    __syncthreads();
    int cg = threadIdx.x & 15;
    int rg = threadIdx.x >> 4;
    int r0 = blockIdx.x * 128 + rg * 8;
    int ca = cg * 4, cb = 64 + cg * 4;
    float acc[8][8] = {};
    for (int k = 0; k < F; k += 4) {
        float4 xv[8];
#pragma unroll
        for (int j = 0; j < 8; ++j) {
            int r = r0 + j; if (r >= N) r = N - 1;   // clamp: safe duplicate read
            xv[j] = *(const float4*)&X[r * F + k];
        }
#pragma unroll
        for (int kk = 0; kk < 4; ++kk) {
            float4 wa = *(const float4*)&Wl[(k + kk) * F + ca];
            float4 wb = *(const float4*)&Wl[(k + kk) * F + cb];
#pragma unroll
            for (int j = 0; j < 8; ++j) {
                float xs = (&xv[j].x)[kk];
                acc[j][0] += xs * wa.x; acc[j][1] += xs * wa.y; acc[j][2] += xs * wa.z; acc[j][3] += xs * wa.w;
                acc[j][4] += xs * wb.x; acc[j][5] += xs * wb.y; acc[j][6] += xs * wb.z; acc[j][7] += xs * wb.w;
            }
        }
    }
#pragma unroll
    for (int j = 0; j < 8; ++j) {
        int r = r0 + j;
        if (r < N) {
            *(float4*)&Y[r * F + ca] = make_float4(acc[j][0], acc[j][1], acc[j][2], acc[j][3]);
            *(float4*)&Y[r * F + cb] = make_float4(acc[j][4], acc[j][5], acc[j][6], acc[j][7]);
        }
    }
}

// ---------------- layer-1 aggregation fused with z = relu(agg+b1) . w2l ----------------
// 32 lanes per node (float4), edge loop unrolled x4 for memory-level parallelism.
// h1 is never materialized.
__global__ __launch_bounds__(256) void k_agg_z(const float* __restrict__ hW, const float* __restrict__ dis,
                                               const int* __restrict__ rowptr, const int* __restrict__ srcs,
                                               const float* __restrict__ enorm, const float* __restrict__ bias,
                                               const float* __restrict__ w2l, float* __restrict__ z, int N) {
    int node = blockIdx.x * 8 + (threadIdx.x >> 5);
    if (node >= N) return;
    int lane = threadIdx.x & 31;
    float di = dis[node];
    float sl = di * di;                       // self-loop norm
    float4 acc = *(const float4*)&hW[node * F + lane * 4];
    float4 b = *(const float4*)&bias[lane * 4];
    acc.x = acc.x * sl + b.x; acc.y = acc.y * sl + b.y;
    acc.z = acc.z * sl + b.z; acc.w = acc.w * sl + b.w;
    int e0 = rowptr[node], e1 = rowptr[node + 1];
    int e = e0;
    for (; e + 4 <= e1; e += 4) {
        int s0 = srcs[e], s1 = srcs[e + 1], s2 = srcs[e + 2], s3 = srcs[e + 3];
        float n0 = enorm[e], n1 = enorm[e + 1], n2 = enorm[e + 2], n3 = enorm[e + 3];
        float4 v0 = *(const float4*)&hW[s0 * F + lane * 4];
        float4 v1 = *(const float4*)&hW[s1 * F + lane * 4];
        float4 v2 = *(const float4*)&hW[s2 * F + lane * 4];
        float4 v3 = *(const float4*)&hW[s3 * F + lane * 4];
        acc.x += n0 * v0.x + n1 * v1.x + n2 * v2.x + n3 * v3.x;
        acc.y += n0 * v0.y + n1 * v1.y + n2 * v2.y + n3 * v3.y;
        acc.z += n0 * v0.z + n1 * v1.z + n2 * v2.z + n3 * v3.z;
        acc.w += n0 * v0.w + n1 * v1.w + n2 * v2.w + n3 * v3.w;
    }
    for (; e < e1; ++e) {
        int s = srcs[e]; float nm = enorm[e];
        float4 v = *(const float4*)&hW[s * F + lane * 4];
        acc.x += nm * v.x; acc.y += nm * v.y; acc.z += nm * v.z; acc.w += nm * v.w;
    }
    // relu
    acc.x = fmaxf(acc.x, 0.0f); acc.y = fmaxf(acc.y, 0.0f);
    acc.z = fmaxf(acc.z, 0.0f); acc.w = fmaxf(acc.w, 0.0f);
    // dot with w2l, reduce over 32 lanes
    float4 w = *(const float4*)&w2l[lane * 4];
    float p = acc.x * w.x + acc.y * w.y + acc.z * w.z + acc.w * w.w;
#pragma unroll
    for (int d = 1; d < 32; d <<= 1) p += __shfl_xor(p, d);
    if (lane == 0) z[node] = p;
}

// ---------------- layer-2 scalar aggregation + mean-pool ----------------
// y[n] = dis[n]^2 z[n] + sum_e enorm z[src]; gacc[batch[n]] += y[n]
__global__ __launch_bounds__(256) void k_pool_z(const float* __restrict__ z, const float* __restrict__ dis,
                                                const int* __restrict__ rowptr, const int* __restrict__ srcs,
                                                const float* __restrict__ enorm, const int* __restrict__ batch,
                                                float* __restrict__ gacc, int N) {
    int n = blockIdx.x * 256 + threadIdx.x;
    float y = 0.0f;
    int b = -1;
    if (n < N) {
        float di = dis[n];
        y = di * di * z[n];
        int e0 = rowptr[n], e1 = rowptr[n + 1];
        int e = e0;
        for (; e + 4 <= e1; e += 4) {
            int s0 = srcs[e], s1 = srcs[e + 1], s2 = srcs[e + 2], s3 = srcs[e + 3];
            y += enorm[e] * z[s0] + enorm[e + 1] * z[s1] + enorm[e + 2] * z[s2] + enorm[e + 3] * z[s3];
        }
        for (; e < e1; ++e) y += enorm[e] * z[srcs[e]];
        b = batch[n];
    }
    // batch is sorted -> if wave endpoints agree, whole wave is one graph
    int bfirst = __shfl(b, 0), blast = __shfl(b, 63);
    if (bfirst == blast && bfirst >= 0) {
#pragma unroll
        for (int d = 1; d < 64; d <<= 1) y += __shfl_xor(y, d);
        if ((threadIdx.x & 63) == 0) unsafeAtomicAdd(&gacc[bfirst], y);
    } else if (n < N) {
        unsafeAtomicAdd(&gacc[b], y);
    }
}

__global__ __launch_bounds__(256) void k_final(const float* __restrict__ gacc, const float* __restrict__ cnt,
                                               const float* __restrict__ cconst, float* __restrict__ out, int G) {
    int g = blockIdx.x * 256 + threadIdx.x;
    if (g < G) out[g] = gacc[g] / fmaxf(cnt[g], 1.0f) + cconst[0];
}

// ---------------- launch ----------------

extern "C" void kernel_launch(void* const* d_in, const int* in_sizes, int n_in,
                              void* d_out, int out_size, void* d_ws, size_t ws_size,
                              hipStream_t stream) {
    const float* x    = (const float*)d_in[0];
    const int*   ei   = (const int*)d_in[1];
    const int*   batch= (const int*)d_in[2];
    const float* W1   = (const float*)d_in[3];
    const float* b1   = (const float*)d_in[4];
    const float* W2   = (const float*)d_in[5];
    const float* b2   = (const float*)d_in[6];
    const float* Wlin = (const float*)d_in[7];
    const float* blin = (const float*)d_in[8];
    float* out = (float*)d_out;

    const int N = in_sizes[2];          // 100000
    const int E = in_sizes[1] / 2;      // 600000
    const int G = out_size;             // 512
    const int* src = ei;
    const int* dst = ei + E;

    // workspace carve-up (256B aligned)
    char* p = (char*)d_ws;
    auto take = [&](size_t bytes) { char* q = p; p += (bytes + 255) & ~(size_t)255; return q; };
    float* bufA   = (float*)take((size_t)N * F * 4);   // hW = x @ W1
    float* zbuf   = (float*)take((size_t)N * 4);
    float* deg    = (float*)take((size_t)N * 4);
    float* dis    = (float*)take((size_t)N * 4);
    int*   rowptr = (int*)  take((size_t)(N + 1) * 4);
    int*   cursor = (int*)  take((size_t)N * 4);
    int*   srcs   = (int*)  take((size_t)E * 4);
    float* enorm  = (float*)take((size_t)E * 4);
    int*   bsum   = (int*)  take(4096);
    float* cnt    = (float*)take((size_t)G * 4);
    float* gacc   = (float*)take((size_t)G * 4);
    float* w2l    = (float*)take((size_t)F * 4);
    float* cconst = (float*)take(256);

    const int nbN = (N + 255) / 256;
    const int nbE = (E + 255) / 256;
    const int nbS = (N + 1023) / 1024;

    k_init <<<nbN, 256, 0, stream>>>(deg, cnt, gacc, N, G);
    k_count<<<(E > N ? nbE : nbN), 256, 0, stream>>>(dst, batch, deg, cnt, E, N);
    k_dis  <<<nbN, 256, 0, stream>>>(deg, dis, N);
    k_scan1<<<nbS, 256, 0, stream>>>(deg, rowptr, bsum, N);
    k_scan2<<<1, 64, 0, stream>>>(bsum, nbS);
    k_scan3<<<nbN, 256, 0, stream>>>(rowptr, bsum, cursor, N, E);
    k_fill <<<nbE, 256, 0, stream>>>(src, dst, dis, cursor, srcs, enorm, E);
    k_w2l  <<<1, 128, 0, stream>>>(W2, Wlin, b2, blin, w2l, cconst);

    // layer 1 GEMM: hW = x @ W1
    k_gemm<<<(N + 127) / 128, 256, 0, stream>>>(x, W1, bufA, N);
    // fused: h1 = relu(agg(hW)+b1); z = h1 . w2l   (h1 never materialized)
    k_agg_z<<<(N + 7) / 8, 256, 0, stream>>>(bufA, dis, rowptr, srcs, enorm, b1, w2l, zbuf, N);
    // layer-2 scalar aggregation + pooling
    k_pool_z<<<nbN, 256, 0, stream>>>(zbuf, dis, rowptr, srcs, enorm, batch, gacc, N);

    k_final<<<(G + 255) / 256, 256, 0, stream>>>(gacc, cnt, cconst, out, G);
}

// Round 3
// 332.782 us; speedup vs baseline: 2.2519x; 1.2438x over previous
//
#include <hip/hip_runtime.h>

#define F 128

// ---------------- setup kernels ----------------

__global__ __launch_bounds__(256) void k_init(float* deg, float* gacc, int N, int G) {
    int i = blockIdx.x * 256 + threadIdx.x;
    if (i < N) deg[i] = 1.0f;               // self-loop
    if (i < G) gacc[i] = 0.0f;
}

// degree count only: random-address atomics, low contention
__global__ __launch_bounds__(256) void k_count(const int* __restrict__ dst, float* deg, int E) {
    int i = blockIdx.x * 256 + threadIdx.x;
    if (i < E) unsafeAtomicAdd(&deg[dst[i]], 1.0f);
}

// graph node counts via binary search (batch is sorted) — no atomics
__global__ __launch_bounds__(256) void k_cnt(const int* __restrict__ batch, float* __restrict__ cnt,
                                             int N, int G) {
    int g = blockIdx.x * 256 + threadIdx.x;
    if (g >= G) return;
    int lo0 = 0, hi = N;
    while (lo0 < hi) { int mid = (lo0 + hi) >> 1; if (batch[mid] < g) lo0 = mid + 1; else hi = mid; }
    int lo1 = lo0; hi = N;
    while (lo1 < hi) { int mid = (lo1 + hi) >> 1; if (batch[mid] < g + 1) lo1 = mid + 1; else hi = mid; }
    cnt[g] = (float)(lo1 - lo0);
}

__global__ __launch_bounds__(256) void k_dis(const float* __restrict__ deg, float* __restrict__ dis, int N) {
    int i = blockIdx.x * 256 + threadIdx.x;
    if (i < N) dis[i] = rsqrtf(deg[i]);     // deg >= 1 always (self-loop)
}

// exclusive scan of (deg[i]-1) = real in-degree, 1024 elems/block
__global__ __launch_bounds__(256) void k_scan1(const float* __restrict__ deg, int* __restrict__ pref,
                                               int* __restrict__ bsum, int N) {
    int t = threadIdx.x;
    int base = blockIdx.x * 1024 + t * 4;
    int v[4]; int s = 0;
#pragma unroll
    for (int j = 0; j < 4; ++j) { int idx = base + j; v[j] = (idx < N) ? ((int)deg[idx] - 1) : 0; s += v[j]; }
    int lane = t & 63, w = t >> 6;
    int inc = s;
#pragma unroll
    for (int d = 1; d < 64; d <<= 1) { int o = __shfl_up(inc, d); if (lane >= d) inc += o; }
    __shared__ int wtot[4];
    if (lane == 63) wtot[w] = inc;
    __syncthreads();
    int woff = 0;
#pragma unroll
    for (int i = 0; i < 4; ++i) if (i < w) woff += wtot[i];
    int run = woff + inc - s;               // exclusive prefix of this thread's chunk
#pragma unroll
    for (int j = 0; j < 4; ++j) { int idx = base + j; if (idx < N) pref[idx] = run; run += v[j]; }
    if (t == 255) bsum[blockIdx.x] = woff + inc;
}

__global__ void k_scan2(int* bsum, int B) {
    if (threadIdx.x == 0) { int run = 0; for (int i = 0; i < B; ++i) { int x = bsum[i]; bsum[i] = run; run += x; } }
}

__global__ __launch_bounds__(256) void k_scan3(int* __restrict__ pref, const int* __restrict__ bsum,
                                               int* __restrict__ cursor, int N, int E) {
    int i = blockIdx.x * 256 + threadIdx.x;
    if (i < N) {
        int v = pref[i] + bsum[i >> 10];
        pref[i] = v;
        cursor[i] = v;
    }
    if (i == 0) pref[N] = E;
}

__global__ __launch_bounds__(256) void k_fill(const int* __restrict__ src, const int* __restrict__ dst,
                                              const float* __restrict__ dis, int* __restrict__ cursor,
                                              int* __restrict__ srcs, float* __restrict__ enorm, int E) {
    int e = blockIdx.x * 256 + threadIdx.x;
    if (e < E) {
        int s = src[e], d = dst[e];
        int slot = atomicAdd(&cursor[d], 1);
        srcs[slot] = s;
        enorm[slot] = dis[s] * dis[d];
    }
}

// w2l = W2 @ Wlin  (128x1); cconst = b2 . Wlin + blin
__global__ __launch_bounds__(128) void k_w2l(const float* __restrict__ W2, const float* __restrict__ Wlin,
                                             const float* __restrict__ b2, const float* __restrict__ blin,
                                             float* __restrict__ w2l, float* __restrict__ cconst) {
    int k = threadIdx.x;
    float s = 0.0f;
    for (int j = 0; j < F; j += 4) {
        float4 w = *(const float4*)&W2[k * F + j];
        float4 l = *(const float4*)&Wlin[j];
        s += w.x * l.x + w.y * l.y + w.z * l.z + w.w * l.w;
    }
    w2l[k] = s;
    __shared__ float sh[F];
    sh[k] = b2[k] * Wlin[k];
    __syncthreads();
    if (k == 0) {
        float c = blin[0];
        for (int j = 0; j < F; ++j) c += sh[j];
        *cconst = c;
    }
}

// ---------------- GEMM: Y[N x 128] = X[N x 128] @ W[128 x 128] ----------------
__global__ __launch_bounds__(256) void k_gemm(const float* __restrict__ X, const float* __restrict__ W,
                                              float* __restrict__ Y, int N) {
    __shared__ float Wl[F * F];
    for (int i = threadIdx.x * 4; i < F * F; i += 256 * 4)
        *(float4*)&Wl[i] = *(const float4*)&W[i];
    __syncthreads();
    int cg = threadIdx.x & 15;
    int rg = threadIdx.x >> 4;
    int r0 = blockIdx.x * 128 + rg * 8;
    int ca = cg * 4, cb = 64 + cg * 4;
    float acc[8][8] = {};
    for (int k = 0; k < F; k += 4) {
        float4 xv[8];
#pragma unroll
        for (int j = 0; j < 8; ++j) {
            int r = r0 + j; if (r >= N) r = N - 1;   // clamp: safe duplicate read
            xv[j] = *(const float4*)&X[r * F + k];
        }
#pragma unroll
        for (int kk = 0; kk < 4; ++kk) {
            float4 wa = *(const float4*)&Wl[(k + kk) * F + ca];
            float4 wb = *(const float4*)&Wl[(k + kk) * F + cb];
#pragma unroll
            for (int j = 0; j < 8; ++j) {
                float xs = (&xv[j].x)[kk];
                acc[j][0] += xs * wa.x; acc[j][1] += xs * wa.y; acc[j][2] += xs * wa.z; acc[j][3] += xs * wa.w;
                acc[j][4] += xs * wb.x; acc[j][5] += xs * wb.y; acc[j][6] += xs * wb.z; acc[j][7] += xs * wb.w;
            }
        }
    }
#pragma unroll
    for (int j = 0; j < 8; ++j) {
        int r = r0 + j;
        if (r < N) {
            *(float4*)&Y[r * F + ca] = make_float4(acc[j][0], acc[j][1], acc[j][2], acc[j][3]);
            *(float4*)&Y[r * F + cb] = make_float4(acc[j][4], acc[j][5], acc[j][6], acc[j][7]);
        }
    }
}

// ---------------- layer-1 aggregation fused with z = relu(agg+b1) . w2l ----------------
// 32 lanes per node (float4), edge loop unrolled x4 for memory-level parallelism.
// h1 is never materialized.
__global__ __launch_bounds__(256) void k_agg_z(const float* __restrict__ hW, const float* __restrict__ dis,
                                               const int* __restrict__ rowptr, const int* __restrict__ srcs,
                                               const float* __restrict__ enorm, const float* __restrict__ bias,
                                               const float* __restrict__ w2l, float* __restrict__ z, int N) {
    int node = blockIdx.x * 8 + (threadIdx.x >> 5);
    if (node >= N) return;
    int lane = threadIdx.x & 31;
    float di = dis[node];
    float sl = di * di;                       // self-loop norm
    float4 acc = *(const float4*)&hW[node * F + lane * 4];
    float4 b = *(const float4*)&bias[lane * 4];
    acc.x = acc.x * sl + b.x; acc.y = acc.y * sl + b.y;
    acc.z = acc.z * sl + b.z; acc.w = acc.w * sl + b.w;
    int e0 = rowptr[node], e1 = rowptr[node + 1];
    int e = e0;
    for (; e + 4 <= e1; e += 4) {
        int s0 = srcs[e], s1 = srcs[e + 1], s2 = srcs[e + 2], s3 = srcs[e + 3];
        float n0 = enorm[e], n1 = enorm[e + 1], n2 = enorm[e + 2], n3 = enorm[e + 3];
        float4 v0 = *(const float4*)&hW[s0 * F + lane * 4];
        float4 v1 = *(const float4*)&hW[s1 * F + lane * 4];
        float4 v2 = *(const float4*)&hW[s2 * F + lane * 4];
        float4 v3 = *(const float4*)&hW[s3 * F + lane * 4];
        acc.x += n0 * v0.x + n1 * v1.x + n2 * v2.x + n3 * v3.x;
        acc.y += n0 * v0.y + n1 * v1.y + n2 * v2.y + n3 * v3.y;
        acc.z += n0 * v0.z + n1 * v1.z + n2 * v2.z + n3 * v3.z;
        acc.w += n0 * v0.w + n1 * v1.w + n2 * v2.w + n3 * v3.w;
    }
    for (; e < e1; ++e) {
        int s = srcs[e]; float nm = enorm[e];
        float4 v = *(const float4*)&hW[s * F + lane * 4];
        acc.x += nm * v.x; acc.y += nm * v.y; acc.z += nm * v.z; acc.w += nm * v.w;
    }
    // relu
    acc.x = fmaxf(acc.x, 0.0f); acc.y = fmaxf(acc.y, 0.0f);
    acc.z = fmaxf(acc.z, 0.0f); acc.w = fmaxf(acc.w, 0.0f);
    // dot with w2l, reduce over 32 lanes
    float4 w = *(const float4*)&w2l[lane * 4];
    float p = acc.x * w.x + acc.y * w.y + acc.z * w.z + acc.w * w.w;
#pragma unroll
    for (int d = 1; d < 32; d <<= 1) p += __shfl_xor(p, d);
    if (lane == 0) z[node] = p;
}

// ---------------- layer-2 scalar aggregation + mean-pool ----------------
__global__ __launch_bounds__(256) void k_pool_z(const float* __restrict__ z, const float* __restrict__ dis,
                                                const int* __restrict__ rowptr, const int* __restrict__ srcs,
                                                const float* __restrict__ enorm, const int* __restrict__ batch,
                                                float* __restrict__ gacc, int N) {
    int n = blockIdx.x * 256 + threadIdx.x;
    float y = 0.0f;
    int b = -1;
    if (n < N) {
        float di = dis[n];
        y = di * di * z[n];
        int e0 = rowptr[n], e1 = rowptr[n + 1];
        int e = e0;
        for (; e + 4 <= e1; e += 4) {
            int s0 = srcs[e], s1 = srcs[e + 1], s2 = srcs[e + 2], s3 = srcs[e + 3];
            y += enorm[e] * z[s0] + enorm[e + 1] * z[s1] + enorm[e + 2] * z[s2] + enorm[e + 3] * z[s3];
        }
        for (; e < e1; ++e) y += enorm[e] * z[srcs[e]];
        b = batch[n];
    }
    // batch is sorted -> if wave endpoints agree, whole wave is one graph
    int bfirst = __shfl(b, 0), blast = __shfl(b, 63);
    if (bfirst == blast && bfirst >= 0) {
#pragma unroll
        for (int d = 1; d < 64; d <<= 1) y += __shfl_xor(y, d);
        if ((threadIdx.x & 63) == 0) unsafeAtomicAdd(&gacc[bfirst], y);
    } else if (n < N) {
        unsafeAtomicAdd(&gacc[b], y);
    }
}

__global__ __launch_bounds__(256) void k_final(const float* __restrict__ gacc, const float* __restrict__ cnt,
                                               const float* __restrict__ cconst, float* __restrict__ out, int G) {
    int g = blockIdx.x * 256 + threadIdx.x;
    if (g < G) out[g] = gacc[g] / fmaxf(cnt[g], 1.0f) + cconst[0];
}

// ---------------- launch ----------------

extern "C" void kernel_launch(void* const* d_in, const int* in_sizes, int n_in,
                              void* d_out, int out_size, void* d_ws, size_t ws_size,
                              hipStream_t stream) {
    const float* x    = (const float*)d_in[0];
    const int*   ei   = (const int*)d_in[1];
    const int*   batch= (const int*)d_in[2];
    const float* W1   = (const float*)d_in[3];
    const float* b1   = (const float*)d_in[4];
    const float* W2   = (const float*)d_in[5];
    const float* b2   = (const float*)d_in[6];
    const float* Wlin = (const float*)d_in[7];
    const float* blin = (const float*)d_in[8];
    float* out = (float*)d_out;

    const int N = in_sizes[2];          // 100000
    const int E = in_sizes[1] / 2;      // 600000
    const int G = out_size;             // 512
    const int* src = ei;
    const int* dst = ei + E;

    // workspace carve-up (256B aligned)
    char* p = (char*)d_ws;
    auto take = [&](size_t bytes) { char* q = p; p += (bytes + 255) & ~(size_t)255; return q; };
    float* bufA   = (float*)take((size_t)N * F * 4);   // hW = x @ W1
    float* zbuf   = (float*)take((size_t)N * 4);
    float* deg    = (float*)take((size_t)N * 4);
    float* dis    = (float*)take((size_t)N * 4);
    int*   rowptr = (int*)  take((size_t)(N + 1) * 4);
    int*   cursor = (int*)  take((size_t)N * 4);
    int*   srcs   = (int*)  take((size_t)E * 4);
    float* enorm  = (float*)take((size_t)E * 4);
    int*   bsum   = (int*)  take(4096);
    float* cnt    = (float*)take((size_t)G * 4);
    float* gacc   = (float*)take((size_t)G * 4);
    float* w2l    = (float*)take((size_t)F * 4);
    float* cconst = (float*)take(256);

    const int nbN = (N + 255) / 256;
    const int nbE = (E + 255) / 256;
    const int nbS = (N + 1023) / 1024;

    k_init <<<nbN, 256, 0, stream>>>(deg, gacc, N, G);
    k_count<<<nbE, 256, 0, stream>>>(dst, deg, E);
    k_cnt  <<<(G + 255) / 256, 256, 0, stream>>>(batch, cnt, N, G);
    k_dis  <<<nbN, 256, 0, stream>>>(deg, dis, N);
    k_scan1<<<nbS, 256, 0, stream>>>(deg, rowptr, bsum, N);
    k_scan2<<<1, 64, 0, stream>>>(bsum, nbS);
    k_scan3<<<nbN, 256, 0, stream>>>(rowptr, bsum, cursor, N, E);
    k_fill <<<nbE, 256, 0, stream>>>(src, dst, dis, cursor, srcs, enorm, E);
    k_w2l  <<<1, 128, 0, stream>>>(W2, Wlin, b2, blin, w2l, cconst);

    // layer 1 GEMM: hW = x @ W1
    k_gemm<<<(N + 127) / 128, 256, 0, stream>>>(x, W1, bufA, N);
    // fused: h1 = relu(agg(hW)+b1); z = h1 . w2l   (h1 never materialized)
    k_agg_z<<<(N + 7) / 8, 256, 0, stream>>>(bufA, dis, rowptr, srcs, enorm, b1, w2l, zbuf, N);
    // layer-2 scalar aggregation + pooling
    k_pool_z<<<nbN, 256, 0, stream>>>(zbuf, dis, rowptr, srcs, enorm, batch, gacc, N);

    k_final<<<(G + 255) / 256, 256, 0, stream>>>(gacc, cnt, cconst, out, G);
}

// Round 4
// 319.561 us; speedup vs baseline: 2.3450x; 1.0414x over previous
//
#include <hip/hip_runtime.h>

#define F 128

typedef __bf16 bf16x8 __attribute__((ext_vector_type(8)));
typedef float f32x4 __attribute__((ext_vector_type(4)));

// ---------------- setup kernels ----------------

__global__ __launch_bounds__(256) void k_init(float* deg, float* gacc, int N, int G) {
    int i = blockIdx.x * 256 + threadIdx.x;
    if (i < N) deg[i] = 1.0f;               // self-loop
    if (i < G) gacc[i] = 0.0f;
}

// degree count only: random-address atomics, low contention
__global__ __launch_bounds__(256) void k_count(const int* __restrict__ dst, float* deg, int E) {
    int i = blockIdx.x * 256 + threadIdx.x;
    if (i < E) unsafeAtomicAdd(&deg[dst[i]], 1.0f);
}

// graph node counts via binary search (batch is sorted) — no atomics
__global__ __launch_bounds__(256) void k_cnt(const int* __restrict__ batch, float* __restrict__ cnt,
                                             int N, int G) {
    int g = blockIdx.x * 256 + threadIdx.x;
    if (g >= G) return;
    int lo0 = 0, hi = N;
    while (lo0 < hi) { int mid = (lo0 + hi) >> 1; if (batch[mid] < g) lo0 = mid + 1; else hi = mid; }
    int lo1 = lo0; hi = N;
    while (lo1 < hi) { int mid = (lo1 + hi) >> 1; if (batch[mid] < g + 1) lo1 = mid + 1; else hi = mid; }
    cnt[g] = (float)(lo1 - lo0);
}

__global__ __launch_bounds__(256) void k_dis(const float* __restrict__ deg, float* __restrict__ dis, int N) {
    int i = blockIdx.x * 256 + threadIdx.x;
    if (i < N) dis[i] = rsqrtf(deg[i]);     // deg >= 1 always (self-loop)
}

// exclusive scan of (deg[i]-1) = real in-degree, 1024 elems/block
__global__ __launch_bounds__(256) void k_scan1(const float* __restrict__ deg, int* __restrict__ pref,
                                               int* __restrict__ bsum, int N) {
    int t = threadIdx.x;
    int base = blockIdx.x * 1024 + t * 4;
    int v[4]; int s = 0;
#pragma unroll
    for (int j = 0; j < 4; ++j) { int idx = base + j; v[j] = (idx < N) ? ((int)deg[idx] - 1) : 0; s += v[j]; }
    int lane = t & 63, w = t >> 6;
    int inc = s;
#pragma unroll
    for (int d = 1; d < 64; d <<= 1) { int o = __shfl_up(inc, d); if (lane >= d) inc += o; }
    __shared__ int wtot[4];
    if (lane == 63) wtot[w] = inc;
    __syncthreads();
    int woff = 0;
#pragma unroll
    for (int i = 0; i < 4; ++i) if (i < w) woff += wtot[i];
    int run = woff + inc - s;               // exclusive prefix of this thread's chunk
#pragma unroll
    for (int j = 0; j < 4; ++j) { int idx = base + j; if (idx < N) pref[idx] = run; run += v[j]; }
    if (t == 255) bsum[blockIdx.x] = woff + inc;
}

__global__ void k_scan2(int* bsum, int B) {
    if (threadIdx.x == 0) { int run = 0; for (int i = 0; i < B; ++i) { int x = bsum[i]; bsum[i] = run; run += x; } }
}

__global__ __launch_bounds__(256) void k_scan3(int* __restrict__ pref, const int* __restrict__ bsum,
                                               int* __restrict__ cursor, int N, int E) {
    int i = blockIdx.x * 256 + threadIdx.x;
    if (i < N) {
        int v = pref[i] + bsum[i >> 10];
        pref[i] = v;
        cursor[i] = v;
    }
    if (i == 0) pref[N] = E;
}

__global__ __launch_bounds__(256) void k_fill(const int* __restrict__ src, const int* __restrict__ dst,
                                              const float* __restrict__ dis, int* __restrict__ cursor,
                                              int* __restrict__ srcs, float* __restrict__ enorm, int E) {
    int e = blockIdx.x * 256 + threadIdx.x;
    if (e < E) {
        int s = src[e], d = dst[e];
        int slot = atomicAdd(&cursor[d], 1);
        srcs[slot] = s;
        enorm[slot] = dis[s] * dis[d];
    }
}

// w2l = W2 @ Wlin  (128x1); cconst = b2 . Wlin + blin
__global__ __launch_bounds__(128) void k_w2l(const float* __restrict__ W2, const float* __restrict__ Wlin,
                                             const float* __restrict__ b2, const float* __restrict__ blin,
                                             float* __restrict__ w2l, float* __restrict__ cconst) {
    int k = threadIdx.x;
    float s = 0.0f;
    for (int j = 0; j < F; j += 4) {
        float4 w = *(const float4*)&W2[k * F + j];
        float4 l = *(const float4*)&Wlin[j];
        s += w.x * l.x + w.y * l.y + w.z * l.z + w.w * l.w;
    }
    w2l[k] = s;
    __shared__ float sh[F];
    sh[k] = b2[k] * Wlin[k];
    __syncthreads();
    if (k == 0) {
        float c = blin[0];
        for (int j = 0; j < F; ++j) c += sh[j];
        *cconst = c;
    }
}

// W[k][n] fp32 -> WT[n][k] split bf16 (hi + residual lo)
__global__ __launch_bounds__(256) void k_wconv(const float* __restrict__ W,
                                               __bf16* __restrict__ WTh, __bf16* __restrict__ WTl) {
    int idx = blockIdx.x * 256 + threadIdx.x;     // 16384 elements
    int k = idx >> 7, n = idx & 127;
    float w = W[idx];
    __bf16 h = (__bf16)w;
    WTh[n * F + k] = h;
    WTl[n * F + k] = (__bf16)(w - (float)h);
}

// ---------------- MFMA GEMM: Y[N x 128] = X[N x 128] @ W[128 x 128] ----------------
// split-bf16 (hi+lo), 3 MFMA products per tile: hh + lh + hl  (ll term ~2^-18, dropped)
// No LDS: B-fragments (W^T rows) read from global, L2-resident (64 KB).
__global__ __launch_bounds__(256) void k_gemm_mfma(const float* __restrict__ X,
                                                   const __bf16* __restrict__ WTh,
                                                   const __bf16* __restrict__ WTl,
                                                   float* __restrict__ Y, int N) {
    int lane = threadIdx.x & 63, wave = threadIdx.x >> 6;
    int quad = lane >> 4, mrow = lane & 15;
    int r0 = blockIdx.x * 128 + wave * 32;        // wave: rows r0..r0+31 (2 row-tiles)

    f32x4 acc[2][8];
#pragma unroll
    for (int rt = 0; rt < 2; ++rt)
#pragma unroll
        for (int c = 0; c < 8; ++c) acc[rt][c] = (f32x4)0.0f;

    int ra = r0 + mrow;       if (ra >= N) ra = N - 1;   // clamp: duplicate read, store guarded
    int rb = r0 + 16 + mrow;  if (rb >= N) rb = N - 1;
    const float* pxa = &X[(size_t)ra * F + quad * 8];
    const float* pxb = &X[(size_t)rb * F + quad * 8];

#pragma unroll 1
    for (int t = 0; t < 4; ++t) {
        int k0 = t * 32 + quad * 8;
        // A fragments: 8 consecutive fp32 from own row, split to bf16 hi/lo
        float4 xa0 = *(const float4*)(pxa + t * 32);
        float4 xa1 = *(const float4*)(pxa + t * 32 + 4);
        float4 xb0 = *(const float4*)(pxb + t * 32);
        float4 xb1 = *(const float4*)(pxb + t * 32 + 4);
        float fa[8] = {xa0.x, xa0.y, xa0.z, xa0.w, xa1.x, xa1.y, xa1.z, xa1.w};
        float fb[8] = {xb0.x, xb0.y, xb0.z, xb0.w, xb1.x, xb1.y, xb1.z, xb1.w};
        bf16x8 ah0, al0, ah1, al1;
#pragma unroll
        for (int j = 0; j < 8; ++j) {
            __bf16 h0 = (__bf16)fa[j]; ah0[j] = h0; al0[j] = (__bf16)(fa[j] - (float)h0);
            __bf16 h1 = (__bf16)fb[j]; ah1[j] = h1; al1[j] = (__bf16)(fb[j] - (float)h1);
        }
        const __bf16* bhp = WTh + k0;
        const __bf16* blp = WTl + k0;
#pragma unroll
        for (int c = 0; c < 8; ++c) {
            int off = (c * 16 + mrow) * F;
            bf16x8 bh = *(const bf16x8*)(bhp + off);
            bf16x8 bl = *(const bf16x8*)(blp + off);
            acc[0][c] = __builtin_amdgcn_mfma_f32_16x16x32_bf16(ah0, bh, acc[0][c], 0, 0, 0);
            acc[1][c] = __builtin_amdgcn_mfma_f32_16x16x32_bf16(ah1, bh, acc[1][c], 0, 0, 0);
            acc[0][c] = __builtin_amdgcn_mfma_f32_16x16x32_bf16(al0, bh, acc[0][c], 0, 0, 0);
            acc[1][c] = __builtin_amdgcn_mfma_f32_16x16x32_bf16(al1, bh, acc[1][c], 0, 0, 0);
            acc[0][c] = __builtin_amdgcn_mfma_f32_16x16x32_bf16(ah0, bl, acc[0][c], 0, 0, 0);
            acc[1][c] = __builtin_amdgcn_mfma_f32_16x16x32_bf16(ah1, bl, acc[1][c], 0, 0, 0);
        }
    }

    // C/D layout: col = lane&15, row = quad*4 + reg
#pragma unroll
    for (int rt = 0; rt < 2; ++rt) {
        int rbase = r0 + rt * 16 + quad * 4;
#pragma unroll
        for (int r = 0; r < 4; ++r) {
            int row = rbase + r;
            if (row < N) {
#pragma unroll
                for (int c = 0; c < 8; ++c)
                    Y[(size_t)row * F + c * 16 + mrow] = acc[rt][c][r];
            }
        }
    }
}

// ---------------- layer-1 aggregation fused with z = relu(agg+b1) . w2l ----------------
__global__ __launch_bounds__(256) void k_agg_z(const float* __restrict__ hW, const float* __restrict__ dis,
                                               const int* __restrict__ rowptr, const int* __restrict__ srcs,
                                               const float* __restrict__ enorm, const float* __restrict__ bias,
                                               const float* __restrict__ w2l, float* __restrict__ z, int N) {
    int node = blockIdx.x * 8 + (threadIdx.x >> 5);
    if (node >= N) return;
    int lane = threadIdx.x & 31;
    float di = dis[node];
    float sl = di * di;                       // self-loop norm
    float4 acc = *(const float4*)&hW[node * F + lane * 4];
    float4 b = *(const float4*)&bias[lane * 4];
    acc.x = acc.x * sl + b.x; acc.y = acc.y * sl + b.y;
    acc.z = acc.z * sl + b.z; acc.w = acc.w * sl + b.w;
    int e0 = rowptr[node], e1 = rowptr[node + 1];
    int e = e0;
    for (; e + 4 <= e1; e += 4) {
        int s0 = srcs[e], s1 = srcs[e + 1], s2 = srcs[e + 2], s3 = srcs[e + 3];
        float n0 = enorm[e], n1 = enorm[e + 1], n2 = enorm[e + 2], n3 = enorm[e + 3];
        float4 v0 = *(const float4*)&hW[s0 * F + lane * 4];
        float4 v1 = *(const float4*)&hW[s1 * F + lane * 4];
        float4 v2 = *(const float4*)&hW[s2 * F + lane * 4];
        float4 v3 = *(const float4*)&hW[s3 * F + lane * 4];
        acc.x += n0 * v0.x + n1 * v1.x + n2 * v2.x + n3 * v3.x;
        acc.y += n0 * v0.y + n1 * v1.y + n2 * v2.y + n3 * v3.y;
        acc.z += n0 * v0.z + n1 * v1.z + n2 * v2.z + n3 * v3.z;
        acc.w += n0 * v0.w + n1 * v1.w + n2 * v2.w + n3 * v3.w;
    }
    for (; e < e1; ++e) {
        int s = srcs[e]; float nm = enorm[e];
        float4 v = *(const float4*)&hW[s * F + lane * 4];
        acc.x += nm * v.x; acc.y += nm * v.y; acc.z += nm * v.z; acc.w += nm * v.w;
    }
    acc.x = fmaxf(acc.x, 0.0f); acc.y = fmaxf(acc.y, 0.0f);
    acc.z = fmaxf(acc.z, 0.0f); acc.w = fmaxf(acc.w, 0.0f);
    float4 w = *(const float4*)&w2l[lane * 4];
    float p = acc.x * w.x + acc.y * w.y + acc.z * w.z + acc.w * w.w;
#pragma unroll
    for (int d = 1; d < 32; d <<= 1) p += __shfl_xor(p, d);
    if (lane == 0) z[node] = p;
}

// ---------------- layer-2 scalar aggregation + mean-pool ----------------
__global__ __launch_bounds__(256) void k_pool_z(const float* __restrict__ z, const float* __restrict__ dis,
                                                const int* __restrict__ rowptr, const int* __restrict__ srcs,
                                                const float* __restrict__ enorm, const int* __restrict__ batch,
                                                float* __restrict__ gacc, int N) {
    int n = blockIdx.x * 256 + threadIdx.x;
    float y = 0.0f;
    int b = -1;
    if (n < N) {
        float di = dis[n];
        y = di * di * z[n];
        int e0 = rowptr[n], e1 = rowptr[n + 1];
        int e = e0;
        for (; e + 4 <= e1; e += 4) {
            int s0 = srcs[e], s1 = srcs[e + 1], s2 = srcs[e + 2], s3 = srcs[e + 3];
            y += enorm[e] * z[s0] + enorm[e + 1] * z[s1] + enorm[e + 2] * z[s2] + enorm[e + 3] * z[s3];
        }
        for (; e < e1; ++e) y += enorm[e] * z[srcs[e]];
        b = batch[n];
    }
    // batch is sorted -> if wave endpoints agree, whole wave is one graph
    int bfirst = __shfl(b, 0), blast = __shfl(b, 63);
    if (bfirst == blast && bfirst >= 0) {
#pragma unroll
        for (int d = 1; d < 64; d <<= 1) y += __shfl_xor(y, d);
        if ((threadIdx.x & 63) == 0) unsafeAtomicAdd(&gacc[bfirst], y);
    } else if (n < N) {
        unsafeAtomicAdd(&gacc[b], y);
    }
}

__global__ __launch_bounds__(256) void k_final(const float* __restrict__ gacc, const float* __restrict__ cnt,
                                               const float* __restrict__ cconst, float* __restrict__ out, int G) {
    int g = blockIdx.x * 256 + threadIdx.x;
    if (g < G) out[g] = gacc[g] / fmaxf(cnt[g], 1.0f) + cconst[0];
}

// ---------------- launch ----------------

extern "C" void kernel_launch(void* const* d_in, const int* in_sizes, int n_in,
                              void* d_out, int out_size, void* d_ws, size_t ws_size,
                              hipStream_t stream) {
    const float* x    = (const float*)d_in[0];
    const int*   ei   = (const int*)d_in[1];
    const int*   batch= (const int*)d_in[2];
    const float* W1   = (const float*)d_in[3];
    const float* b1   = (const float*)d_in[4];
    const float* W2   = (const float*)d_in[5];
    const float* b2   = (const float*)d_in[6];
    const float* Wlin = (const float*)d_in[7];
    const float* blin = (const float*)d_in[8];
    float* out = (float*)d_out;

    const int N = in_sizes[2];          // 100000
    const int E = in_sizes[1] / 2;      // 600000
    const int G = out_size;             // 512
    const int* src = ei;
    const int* dst = ei + E;

    // workspace carve-up (256B aligned)
    char* p = (char*)d_ws;
    auto take = [&](size_t bytes) { char* q = p; p += (bytes + 255) & ~(size_t)255; return q; };
    float*  bufA   = (float*)take((size_t)N * F * 4);   // hW = x @ W1
    float*  zbuf   = (float*)take((size_t)N * 4);
    float*  deg    = (float*)take((size_t)N * 4);
    float*  dis    = (float*)take((size_t)N * 4);
    int*    rowptr = (int*)  take((size_t)(N + 1) * 4);
    int*    cursor = (int*)  take((size_t)N * 4);
    int*    srcs   = (int*)  take((size_t)E * 4);
    float*  enorm  = (float*)take((size_t)E * 4);
    int*    bsum   = (int*)  take(4096);
    float*  cnt    = (float*)take((size_t)G * 4);
    float*  gacc   = (float*)take((size_t)G * 4);
    float*  w2l    = (float*)take((size_t)F * 4);
    float*  cconst = (float*)take(256);
    __bf16* WTh    = (__bf16*)take((size_t)F * F * 2);
    __bf16* WTl    = (__bf16*)take((size_t)F * F * 2);

    const int nbN = (N + 255) / 256;
    const int nbE = (E + 255) / 256;
    const int nbS = (N + 1023) / 1024;

    k_init <<<nbN, 256, 0, stream>>>(deg, gacc, N, G);
    k_count<<<nbE, 256, 0, stream>>>(dst, deg, E);
    k_cnt  <<<(G + 255) / 256, 256, 0, stream>>>(batch, cnt, N, G);
    k_dis  <<<nbN, 256, 0, stream>>>(deg, dis, N);
    k_scan1<<<nbS, 256, 0, stream>>>(deg, rowptr, bsum, N);
    k_scan2<<<1, 64, 0, stream>>>(bsum, nbS);
    k_scan3<<<nbN, 256, 0, stream>>>(rowptr, bsum, cursor, N, E);
    k_fill <<<nbE, 256, 0, stream>>>(src, dst, dis, cursor, srcs, enorm, E);
    k_w2l  <<<1, 128, 0, stream>>>(W2, Wlin, b2, blin, w2l, cconst);
    k_wconv<<<(F * F + 255) / 256, 256, 0, stream>>>(W1, WTh, WTl);

    // layer 1 GEMM (MFMA split-bf16): hW = x @ W1
    k_gemm_mfma<<<(N + 127) / 128, 256, 0, stream>>>(x, WTh, WTl, bufA, N);
    // fused: h1 = relu(agg(hW)+b1); z = h1 . w2l   (h1 never materialized)
    k_agg_z<<<(N + 7) / 8, 256, 0, stream>>>(bufA, dis, rowptr, srcs, enorm, b1, w2l, zbuf, N);
    // layer-2 scalar aggregation + pooling
    k_pool_z<<<nbN, 256, 0, stream>>>(zbuf, dis, rowptr, srcs, enorm, batch, gacc, N);

    k_final<<<(G + 255) / 256, 256, 0, stream>>>(gacc, cnt, cconst, out, G);
}